// Round 12
// baseline (142.708 us; speedup 1.0000x reference)
//
#include <hip/hip_runtime.h>
#include <hip/hip_bf16.h>
#include <stdint.h>

#define D 128
#define MCOLS 196      // 14*14
#define XPITCH 232     // xc pitch (bf16): 196 data + pad to K=224, 16B-aligned rows
#define BPITCH 136     // NS buffer pitch (bf16)
#define KOUT 8256      // 128*129/2

typedef short v8s __attribute__((ext_vector_type(8)));
typedef float v4f __attribute__((ext_vector_type(4)));

__device__ __forceinline__ uint32_t cvtpk(float a, float b) {
    __hip_bfloat162 h = __float22bfloat162_rn(make_float2(a, b));   // v_cvt_pk_bf16_f32
    uint32_t u;
    __builtin_memcpy(&u, &h, 4);
    return u;
}
__device__ __forceinline__ uint64_t pk64(float a, float b, float c, float d) {
    return (uint64_t)cvtpk(a, b) | ((uint64_t)cvtpk(c, d) << 32);
}
__device__ __forceinline__ float unlo(uint32_t u) { return __builtin_bit_cast(float, u << 16); }
__device__ __forceinline__ float unhi(uint32_t u) { return __builtin_bit_cast(float, u & 0xFFFF0000u); }

// Barrier WITHOUT vmcnt drain: keeps prefetch global_loads in flight across
// LDS-ordering barriers. lgkmcnt(0) orders all LDS ops; sched_barrier(0)
// prevents post-barrier ds ops hoisting above s_barrier.
__device__ __forceinline__ void barrier_nd() {
    asm volatile("s_waitcnt lgkmcnt(0)" ::: "memory");
    __builtin_amdgcn_s_barrier();
    __builtin_amdgcn_sched_barrier(0);
}

// Persistent: grid=256 (1 block/CU), 4 batches/block, batch k+1 register-
// prefetched during batch k's NS chain (no-drain barriers). 512 threads =
// 8 waves (2/SIMD, clean 128-VGPR fit per R8).
// SYMMETRY EXPLOITED AT TILE LEVEL: every matrix here (cov, all NS
// intermediates, the output) is symmetric, so only the 36 upper 16x16 tiles
// (of 64) are computed. Each tile is stored TWICE: transposed b64 (fills
// lower LDS cells) + direct 4xb16 scatter for rb<cb (fills upper cells) ->
// LDS holds the full exactly-symmetric matrix for row-major MFMA reads.
// The 36 tiles are rebalanced over all 8 waves (3,7,4,4,4,4,3,7):
//   w0:(0,0..1)x(0,1) upper  w1:(0..3)x(2,3) upper  w2:(0,1)x(4,5)
//   w3:(0,1)x(6,7)  w4:(2,3)x(4,5)  w5:(2,3)x(6,7)  w6:(4,5)x(4,5) upper
//   w7:(4..7)x(6,7) upper
// -25% LDS read bytes, -44% MFMA vs full-matrix R8.
__global__ __launch_bounds__(512) void mpncov_kernel(const float* __restrict__ x,
                                                     float* __restrict__ out) {
    __shared__ __align__(16) uint16_t lds[4 * D * BPITCH];   // 139264 B
    __shared__ float redbuf[8];

    uint16_t* const B0 = lds;
    uint16_t* const B1 = lds + 1 * D * BPITCH;
    uint16_t* const B2 = lds + 2 * D * BPITCH;
    uint16_t* const B3 = lds + 3 * D * BPITCH;
    // xc (128 x 232 bf16 = 59392 B) overlays B1+B2 (69632 B). Rotation:
    // covM=B0, Y1=B1, ZY1=B2, Y2=B3, Z2=B1, T2=B0 -> B2 dead after MM4,
    // B1 dead after MM5 -> pack(k+1) runs during/after MM6.
    uint16_t (*const xc)[XPITCH] = reinterpret_cast<uint16_t(*)[XPITCH]>(B1);
    const uint16_t* const xcf = &xc[0][0];

    const int tid = threadIdx.x;
    const int lane = tid & 63;
    const int w = tid >> 6;
    const int lr = lane & 15, lk = lane >> 4;
    const int pr = tid >> 2, pq = tid & 3;             // prefetch: 4 threads/row

    // ---- wave tile table (wave-uniform scalars) ----
    const int NR  = (w == 1 || w == 7) ? 4 : 2;        // # row-blocks
    const int DG  = (w == 0 || w == 1 || w == 6 || w == 7);  // has diagonal
    const int RB0 = (w >= 6) ? 4 : ((w >= 4) ? 2 : 0); // first row-block
    const int CB0 = (w < 4) ? 2 * w : 4 + 2 * (w & 1); // first col-block
    // tile (i,j) live iff i<NR && !(DG && i==NR-1 && j==0); rb=RB0+i, cb=CB0+j (rb<=cb)
#define LIVE(i, j) ((i) < NR && !(DG && (i) == NR - 1 && (j) == 0))

    // ---- cross-batch prefetch state: 49 float4 per row, 12(+1 tail) per thread ----
    float4 pf[12]; float4 pfT;

    auto issue_pf = [&](int bbn) {
        const float4* p4 = reinterpret_cast<const float4*>(x + (size_t)bbn * (D * MCOLS)) + 49 * pr;
#pragma unroll
        for (int i = 0; i < 12; ++i) pf[i] = p4[pq + 4 * i];
        if (pq == 0) pfT = p4[48];
    };
    // mean via 4-lane shfl, center exactly in f32, pack bf16, write xc + zero K-pad
    auto pack_pf = [&]() {
        float s = 0.f;
#pragma unroll
        for (int i = 0; i < 12; ++i) s += (pf[i].x + pf[i].y) + (pf[i].z + pf[i].w);
        if (pq == 0) s += (pfT.x + pfT.y) + (pfT.z + pfT.w);
        s += __shfl_xor(s, 1); s += __shfl_xor(s, 2);
        const float m = s * (1.0f / MCOLS);
#pragma unroll
        for (int i = 0; i < 12; ++i)
            *reinterpret_cast<uint64_t*>(&xc[pr][4 * (pq + 4 * i)]) =
                pk64(pf[i].x - m, pf[i].y - m, pf[i].z - m, pf[i].w - m);
        if (pq == 0)
            *reinterpret_cast<uint64_t*>(&xc[pr][192]) =
                pk64(pfT.x - m, pfT.y - m, pfT.z - m, pfT.w - m);
        *reinterpret_cast<uint64_t*>(&xc[pr][MCOLS + 4 * pq]) = 0ull;
        if (pq < 3) *reinterpret_cast<uint64_t*>(&xc[pr][MCOLS + 4 * (pq + 4)]) = 0ull;
    };

    v4f acc[4][2];
    auto zacc = [&]() {
#pragma unroll
        for (int i = 0; i < 4; ++i)
#pragma unroll
            for (int j = 0; j < 2; ++j) acc[i][j] = v4f{0.f, 0.f, 0.f, 0.f};
    };
    // acc = P@Q over the wave's live upper tiles (both operands row-read; symmetric)
    auto matmul = [&](const uint16_t* P, const uint16_t* Q, int pitch, int KK) {
        zacc();
        for (int kk = 0; kk < KK; ++kk) {
            const int k0 = kk * 32 + lk * 8;
            v8s af[4], bf[2];
#pragma unroll
            for (int i = 0; i < 4; ++i)
                if (i < NR)
                    af[i] = *reinterpret_cast<const v8s*>(&P[(16 * (RB0 + i) + lr) * pitch + k0]);
#pragma unroll
            for (int j = 0; j < 2; ++j)
                bf[j] = *reinterpret_cast<const v8s*>(&Q[(16 * (CB0 + j) + lr) * pitch + k0]);
#pragma unroll
            for (int i = 0; i < 4; ++i)
#pragma unroll
                for (int j = 0; j < 2; ++j)
                    if (LIVE(i, j))
                        acc[i][j] = __builtin_amdgcn_mfma_f32_16x16x32_bf16(af[i], bf[j], acc[i][j], 0, 0, 0);
        }
    };
    // store tile at (rb,cb): transposed b64 always (fills [c][r], lower cells);
    // direct 4xb16 mirror for strictly-upper (fills [r][c], upper cells).
    auto store_mirror = [&](uint16_t* dst, int rb, int cb, const v4f& v) {
        const int r0 = 16 * rb + 4 * lk;
        const int c  = 16 * cb + lr;
        const uint64_t p = pk64(v[0], v[1], v[2], v[3]);
        *reinterpret_cast<uint64_t*>(&dst[c * BPITCH + r0]) = p;
        if (rb != cb) {
            dst[(r0 + 0) * BPITCH + c] = (uint16_t)p;
            dst[(r0 + 1) * BPITCH + c] = (uint16_t)(p >> 16);
            dst[(r0 + 2) * BPITCH + c] = (uint16_t)(p >> 32);
            dst[(r0 + 3) * BPITCH + c] = (uint16_t)(p >> 48);
        }
    };
    auto own_addr = [&](const uint16_t* src, int rb, int cb) -> const uint64_t* {
        const int r0 = 16 * rb + 4 * lk;
        const int c  = 16 * cb + lr;
        return reinterpret_cast<const uint64_t*>(&src[c * BPITCH + r0]);
    };
    auto unq = [&](uint64_t g) -> v4f {
        return v4f{unlo((uint32_t)g), unhi((uint32_t)g),
                   unlo((uint32_t)(g >> 32)), unhi((uint32_t)(g >> 32))};
    };

    // Generic NS stage: dst = sAcc*(P@Q) + sO1*own1 [+ sO2*own2], own loads hoisted.
    auto stage = [&](const uint16_t* P, const uint16_t* Q, uint16_t* dst,
                     const uint16_t* own1, float sAcc, float sO1,
                     const uint16_t* own2, float sO2) {
        uint64_t g1[4][2], g2[4][2];
#pragma unroll
        for (int i = 0; i < 4; ++i)
#pragma unroll
            for (int j = 0; j < 2; ++j)
                if (LIVE(i, j)) {
                    g1[i][j] = *own_addr(own1, RB0 + i, CB0 + j);
                    if (own2) g2[i][j] = *own_addr(own2, RB0 + i, CB0 + j);
                }
        matmul(P, Q, BPITCH, 4);
#pragma unroll
        for (int i = 0; i < 4; ++i)
#pragma unroll
            for (int j = 0; j < 2; ++j)
                if (LIVE(i, j)) {
                    const v4f o1 = unq(g1[i][j]);
                    v4f v;
#pragma unroll
                    for (int q = 0; q < 4; ++q) v[q] = sAcc * acc[i][j][q] + sO1 * o1[q];
                    if (own2) {
                        const v4f o2 = unq(g2[i][j]);
#pragma unroll
                        for (int q = 0; q < 4; ++q) v[q] += sO2 * o2[q];
                    }
                    store_mirror(dst, RB0 + i, CB0 + j, v);
                }
    };

    // ---- prologue: stage batch (4*blockIdx.x) ----
    issue_pf(4 * blockIdx.x);
    pack_pf();

    for (int it = 0; it < 4; ++it) {
        const int bb = 4 * blockIdx.x + it;
        barrier_nd();                               // xc(bb) ready

        if (it < 3) {                               // issue next batch's loads NOW;
            issue_pf(bb + 1);                       // they stay in flight across all
            __builtin_amdgcn_sched_barrier(0);      // no-drain barriers below
        }

        // ---- cov: covM = xc @ xc^T (centered, K padded to 224), upper tiles ----
        matmul(xcf, xcf, XPITCH, 7);

        // trace from diagonal tiles (C/D layout: col=lane&15, row=(lane>>4)*4+q)
        float tval = 0.f;
        if ((lr >> 2) == lk) {
            const int qq = lr & 3;
#pragma unroll
            for (int i = 0; i < 4; ++i)
#pragma unroll
                for (int j = 0; j < 2; ++j)
                    if (LIVE(i, j) && (RB0 + i == CB0 + j)) tval += acc[i][j][qq];
        }
#pragma unroll
        for (int off = 32; off; off >>= 1) tval += __shfl_down(tval, off);
        if (lane == 0) redbuf[w] = tval;

        // store covM (unnormalized; 1/tr folded into combine scalars below)
#pragma unroll
        for (int i = 0; i < 4; ++i)
#pragma unroll
            for (int j = 0; j < 2; ++j)
                if (LIVE(i, j)) store_mirror(B0, RB0 + i, CB0 + j, acc[i][j]);
        barrier_nd();                               // covM + redbuf visible; xc dead

        const float tr = ((redbuf[0] + redbuf[1]) + (redbuf[2] + redbuf[3])) +
                         ((redbuf[4] + redbuf[5]) + (redbuf[6] + redbuf[7]));
        const float inv = 1.0f / tr;
        const float outscale = sqrtf(tr * (1.0f / MCOLS));

        // MM1: RY1 = -0.5*inv^2*(C@C) + 1.5*inv*C        -> B1
        stage(B0, B0, B1, B0, -0.5f * inv * inv, 1.5f * inv, nullptr, 0.f);
        barrier_nd();
        // MM2: RZY1 = 0.25*inv*(C@RY1) - 0.75*RY1        -> B2
        stage(B0, B1, B2, B1, 0.25f * inv, -0.75f, nullptr, 0.f);
        barrier_nd();
        // MM3: RY2 = RY1@RZY1 + 1.5*RY1                  -> B3
        stage(B1, B2, B3, B1, 1.f, 1.5f, nullptr, 0.f);
        barrier_nd();
        // MM4: RZ2 = -0.5*inv*(RZY1@C) - 0.75*inv*C + 1.5*RZY1  -> B1
        stage(B2, B0, B1, B0, -0.5f * inv, -0.75f * inv, B2, 1.5f);
        barrier_nd();
        // MM5: RT2 = RZ2@RY2 + 2.25*RY2                  -> B0
        stage(B1, B3, B0, B3, 1.f, 2.25f, nullptr, 0.f);
        barrier_nd();                              // T2 ready; B1,B2 (=xc region) dead

        // MM6: O = (1.5*RY2 - 0.5*(RY2@RT2)) * outscale ; upper tiles -> global triu
        {
            uint64_t g[4][2];
#pragma unroll
            for (int i = 0; i < 4; ++i)
#pragma unroll
                for (int j = 0; j < 2; ++j)
                    if (LIVE(i, j)) g[i][j] = *own_addr(B3, RB0 + i, CB0 + j);
            matmul(B3, B0, BPITCH, 4);
            float* ob = out + (size_t)bb * KOUT;
#pragma unroll
            for (int i = 0; i < 4; ++i)
#pragma unroll
                for (int j = 0; j < 2; ++j) {
                    if (!LIVE(i, j)) continue;
                    const int rb = RB0 + i, cb = CB0 + j;
                    const int r0 = 16 * rb + 4 * lk;
                    const int c  = 16 * cb + lr;
                    const v4f o = unq(g[i][j]);
                    float vv[4];
#pragma unroll
                    for (int q = 0; q < 4; ++q)
                        vv[q] = (1.5f * o[q] - 0.5f * acc[i][j][q]) * outscale;
                    if (rb < cb) {
#pragma unroll
                        for (int q = 0; q < 4; ++q) {
                            const int r = r0 + q;
                            ob[r * D - (r * (r + 1)) / 2 + c] = vv[q];
                        }
                    } else {   // diagonal tile
#pragma unroll
                        for (int q = 0; q < 4; ++q) {
                            const int r = r0 + q;
                            if (r <= c) ob[r * D - (r * (r + 1)) / 2 + c] = vv[q];
                        }
                    }
                }
        }
        if (it < 3) pack_pf();                     // xc(bb+1) into B1/B2, overlaps MM6
    }
#undef LIVE
}

extern "C" void kernel_launch(void* const* d_in, const int* in_sizes, int n_in,
                              void* d_out, int out_size, void* d_ws, size_t ws_size,
                              hipStream_t stream) {
    const float* x = (const float*)d_in[0];
    float* out = (float*)d_out;
    mpncov_kernel<<<dim3(256), dim3(512), 0, stream>>>(x, out);
}

// Round 13
// 104.533 us; speedup vs baseline: 1.3652x; 1.3652x over previous
//
#include <hip/hip_runtime.h>
#include <hip/hip_bf16.h>
#include <stdint.h>

#define D 128
#define MCOLS 196      // 14*14
#define XPITCH 232     // xc pitch (bf16): 116 dwords == 20 mod 32 -> 2-way (minimum)
#define BPITCH 136     // NS buffer pitch (bf16): 68 dwords == 4 mod 32 -> 2-way
#define KOUT 8256      // 128*129/2

typedef short v8s __attribute__((ext_vector_type(8)));
typedef float v4f __attribute__((ext_vector_type(4)));

__device__ __forceinline__ uint32_t cvtpk(float a, float b) {
    __hip_bfloat162 h = __float22bfloat162_rn(make_float2(a, b));   // v_cvt_pk_bf16_f32
    uint32_t u;
    __builtin_memcpy(&u, &h, 4);
    return u;
}
__device__ __forceinline__ uint64_t pk64(float a, float b, float c, float d) {
    return (uint64_t)cvtpk(a, b) | ((uint64_t)cvtpk(c, d) << 32);
}
__device__ __forceinline__ float unlo(uint32_t u) { return __builtin_bit_cast(float, u << 16); }
__device__ __forceinline__ float unhi(uint32_t u) { return __builtin_bit_cast(float, u & 0xFFFF0000u); }

// Barrier WITHOUT vmcnt drain: keeps prefetch global_loads in flight across
// LDS-ordering barriers. lgkmcnt(0) orders all LDS ops (stores AND the
// pre-hoisted kk0 operand reads -> their data is in regs before s_barrier);
// sched_barrier(0) prevents post-barrier ds ops hoisting above s_barrier.
__device__ __forceinline__ void barrier_nd() {
    asm volatile("s_waitcnt lgkmcnt(0)" ::: "memory");
    __builtin_amdgcn_s_barrier();
    __builtin_amdgcn_sched_barrier(0);
}

// R8 structure + surgical fixes:
//  - persistent grid=256 (1 block/CU), 4 batches/block, batch k+1 register-
//    prefetched during batch k's NS chain (no-drain barriers)
//  - 512 threads = 8 waves (2/SIMD; the allocator's 128-VGPR budget at this
//    block size is the only spill-free config with prefetch, per R6-R11)
//  - XPITCH=232: cov ds_read_b128 at 224 was ~8-way bank-conflicted
//  - prefetch converted f32->bf16 EARLY (after cov): frees 26 regs; cov runs
//    on UNCENTERED bf16 with exact f32 rank-1 mean fix (R10-validated)
//  - kk0 operand reads of the next stage hoisted BEFORE the barrier whenever
//    the operand buffer is old (MM2/3/4 af, MM5 bf, MM6 af) -> removes the
//    post-barrier ds_read latency stall. WAR-safe: hoisted reads always
//    target a buffer disjoint from the current stage's store destination.
__global__ __launch_bounds__(512) void mpncov_kernel(const float* __restrict__ x,
                                                     float* __restrict__ out) {
    __shared__ __align__(16) uint16_t lds[4 * D * BPITCH];   // 139264 B
    __shared__ __align__(16) float meanv[2][D];
    __shared__ float redbuf[8];

    uint16_t* const B0 = lds;
    uint16_t* const B1 = lds + 1 * D * BPITCH;
    uint16_t* const B2 = lds + 2 * D * BPITCH;
    uint16_t* const B3 = lds + 3 * D * BPITCH;
    // xc (128 x 232 bf16 = 59392 B) overlays B1+B2 (69632 B). Rotation:
    // covM=B0, Y1=B1, ZY1=B2, Y2=B3, Z2=B1, T2=B0 -> B2 dead after MM4,
    // B1 dead after MM5 -> pack(k+1) runs during/after MM6 (reads B3,B0 only).
    uint16_t (*const xc)[XPITCH] = reinterpret_cast<uint16_t(*)[XPITCH]>(B1);

    const int tid = threadIdx.x;
    const int lane = tid & 63;
    const int w = tid >> 6, wr = w >> 2, wc = w & 3;   // 2x4 wave grid, 64x32/wave
    const int lr = lane & 15, lk = lane >> 4;
    const int pr = tid >> 2, pq = tid & 3;             // prefetch: 4 threads/row

    // ---- cross-batch prefetch: 49 float4/row; pf(f32) short-lived, pk(bf16) persistent ----
    float4 pf[12]; float4 pfT;
    uint64_t pk[12]; uint64_t pkT;

    auto issue_pf = [&](int bbn) {
        const float4* p4 = reinterpret_cast<const float4*>(x + (size_t)bbn * (D * MCOLS)) + 49 * pr;
#pragma unroll
        for (int i = 0; i < 12; ++i) pf[i] = p4[pq + 4 * i];
        if (pq == 0) pfT = p4[48];
    };
    // exact f32 row mean via 4-lane shfl -> meanv[nb]; pf -> pk (UNCENTERED bf16)
    auto cvt_and_mean = [&](int nb) {
        float s = 0.f;
#pragma unroll
        for (int i = 0; i < 12; ++i) s += (pf[i].x + pf[i].y) + (pf[i].z + pf[i].w);
        if (pq == 0) s += (pfT.x + pfT.y) + (pfT.z + pfT.w);
        s += __shfl_xor(s, 1); s += __shfl_xor(s, 2);
        if (pq == 0) meanv[nb][pr] = s * (1.0f / MCOLS);
#pragma unroll
        for (int i = 0; i < 12; ++i) pk[i] = pk64(pf[i].x, pf[i].y, pf[i].z, pf[i].w);
        if (pq == 0) pkT = pk64(pfT.x, pfT.y, pfT.z, pfT.w);
    };
    auto pack_pf = [&]() {   // scatter packed bf16 to xc + zero K-pad (cols 196..223)
#pragma unroll
        for (int i = 0; i < 12; ++i)
            *reinterpret_cast<uint64_t*>(&xc[pr][4 * (pq + 4 * i)]) = pk[i];
        if (pq == 0) *reinterpret_cast<uint64_t*>(&xc[pr][192]) = pkT;
        *reinterpret_cast<uint64_t*>(&xc[pr][MCOLS + 4 * pq]) = 0ull;
        if (pq < 3) *reinterpret_cast<uint64_t*>(&xc[pr][MCOLS + 4 * (pq + 4)]) = 0ull;
    };

    v4f acc[4][2];
    auto zacc = [&]() {
#pragma unroll
        for (int i = 0; i < 4; ++i)
#pragma unroll
            for (int j = 0; j < 2; ++j) acc[i][j] = v4f{0.f, 0.f, 0.f, 0.f};
    };

    v8s af0[4];   // hoisted kk0 A-operand (loaded pre-barrier)
    v8s bf0[2];   // hoisted kk0 B-operand
    auto loadA0 = [&](const uint16_t* P) {
#pragma unroll
        for (int i = 0; i < 4; ++i)
            af0[i] = *reinterpret_cast<const v8s*>(&P[(64 * wr + 16 * i + lr) * BPITCH + lk * 8]);
    };
    auto loadB0 = [&](const uint16_t* Q) {
#pragma unroll
        for (int j = 0; j < 2; ++j)
            bf0[j] = *reinterpret_cast<const v8s*>(&Q[(32 * wc + 16 * j + lr) * BPITCH + lk * 8]);
    };

    // acc = P@Q ; preA/preB: use hoisted kk0 operands (pointers are call-site
    // constants -> folded after inlining, like the own2 nullptr pattern)
    auto matmul = [&](const uint16_t* P, const uint16_t* Q, bool preA, bool preB) {
        zacc();
#pragma unroll
        for (int kk = 0; kk < 4; ++kk) {
            const int k0 = kk * 32 + lk * 8;
            v8s af[4], bf[2];
            if (kk == 0 && preA) {
#pragma unroll
                for (int i = 0; i < 4; ++i) af[i] = af0[i];
            } else {
#pragma unroll
                for (int i = 0; i < 4; ++i)
                    af[i] = *reinterpret_cast<const v8s*>(&P[(64 * wr + 16 * i + lr) * BPITCH + k0]);
            }
            if (kk == 0 && preB) {
#pragma unroll
                for (int j = 0; j < 2; ++j) bf[j] = bf0[j];
            } else {
#pragma unroll
                for (int j = 0; j < 2; ++j)
                    bf[j] = *reinterpret_cast<const v8s*>(&Q[(32 * wc + 16 * j + lr) * BPITCH + k0]);
            }
#pragma unroll
            for (int i = 0; i < 4; ++i)
#pragma unroll
                for (int j = 0; j < 2; ++j)
                    acc[i][j] = __builtin_amdgcn_mfma_f32_16x16x32_bf16(af[i], bf[j], acc[i][j], 0, 0, 0);
        }
    };
    auto store_tile = [&](uint16_t* dst, int i, int j, const v4f& v) {   // transposed b64
        const int r0 = 64 * wr + 16 * i + 4 * lk;
        const int c  = 32 * wc + 16 * j + lr;
        *reinterpret_cast<uint64_t*>(&dst[c * BPITCH + r0]) = pk64(v[0], v[1], v[2], v[3]);
    };
    auto own_addr = [&](const uint16_t* src, int i, int j) -> const uint64_t* {
        const int r0 = 64 * wr + 16 * i + 4 * lk;
        const int c  = 32 * wc + 16 * j + lr;
        return reinterpret_cast<const uint64_t*>(&src[c * BPITCH + r0]);
    };
    auto unq = [&](uint64_t g) -> v4f {
        return v4f{unlo((uint32_t)g), unhi((uint32_t)g),
                   unlo((uint32_t)(g >> 32)), unhi((uint32_t)(g >> 32))};
    };

    // Generic NS stage: dst = sAcc*(P@Q) + sO1*own1 [+ sO2*own2]
    auto stage = [&](const uint16_t* P, const uint16_t* Q, uint16_t* dst,
                     const uint16_t* own1, float sAcc, float sO1,
                     const uint16_t* own2, float sO2, bool preA, bool preB) {
        uint64_t g1[4][2], g2[4][2];
#pragma unroll
        for (int i = 0; i < 4; ++i)
#pragma unroll
            for (int j = 0; j < 2; ++j) {
                g1[i][j] = *own_addr(own1, i, j);
                if (own2) g2[i][j] = *own_addr(own2, i, j);
            }
        matmul(P, Q, preA, preB);
#pragma unroll
        for (int i = 0; i < 4; ++i)
#pragma unroll
            for (int j = 0; j < 2; ++j) {
                const v4f o1 = unq(g1[i][j]);
                v4f v;
#pragma unroll
                for (int q = 0; q < 4; ++q) v[q] = sAcc * acc[i][j][q] + sO1 * o1[q];
                if (own2) {
                    const v4f o2 = unq(g2[i][j]);
#pragma unroll
                    for (int q = 0; q < 4; ++q) v[q] += sO2 * o2[q];
                }
                store_tile(dst, i, j, v);
            }
    };

    // ---- prologue: stage batch (4*blockIdx.x); mean -> meanv[0] ----
    issue_pf(4 * blockIdx.x);
    cvt_and_mean(0);
    pack_pf();

    for (int it = 0; it < 4; ++it) {
        const int bb = 4 * blockIdx.x + it;
        const int cur = it & 1, nxt = cur ^ 1;
        barrier_nd();                               // xc(bb) + meanv[cur] ready

        if (it < 3) {                               // issue next batch's loads NOW
            issue_pf(bb + 1);
            __builtin_amdgcn_sched_barrier(0);
        }

        // ---- cov: covM = xc @ xc^T on UNCENTERED bf16 (K padded to 224) ----
        zacc();
#pragma unroll
        for (int kk = 0; kk < 7; ++kk) {
            const int k0 = kk * 32 + lk * 8;
            v8s af[4], bf[2];
#pragma unroll
            for (int i = 0; i < 4; ++i)
                af[i] = *reinterpret_cast<const v8s*>(&xc[64 * wr + 16 * i + lr][k0]);
#pragma unroll
            for (int j = 0; j < 2; ++j)
                bf[j] = *reinterpret_cast<const v8s*>(&xc[32 * wc + 16 * j + lr][k0]);
#pragma unroll
            for (int i = 0; i < 4; ++i)
#pragma unroll
                for (int j = 0; j < 2; ++j)
                    acc[i][j] = __builtin_amdgcn_mfma_f32_16x16x32_bf16(af[i], bf[j], acc[i][j], 0, 0, 0);
        }
        // exact f32 rank-1 centering fix: acc -= M * m_r * m_c
        {
            v4f mrow[4]; float mcol[2];
#pragma unroll
            for (int i = 0; i < 4; ++i)
                mrow[i] = *reinterpret_cast<const v4f*>(&meanv[cur][64 * wr + 16 * i + 4 * lk]);
#pragma unroll
            for (int j = 0; j < 2; ++j) mcol[j] = meanv[cur][32 * wc + 16 * j + lr];
#pragma unroll
            for (int i = 0; i < 4; ++i)
#pragma unroll
                for (int j = 0; j < 2; ++j)
#pragma unroll
                    for (int q = 0; q < 4; ++q)
                        acc[i][j][q] -= (float)MCOLS * mrow[i][q] * mcol[j];
        }

        // trace (C/D layout: col=lane&15, row=(lane>>4)*4+q)
        float tval = 0.f;
        if ((lr >> 2) == lk) {
            const int qq = lr & 3;
#pragma unroll
            for (int i = 0; i < 4; ++i)
#pragma unroll
                for (int j = 0; j < 2; ++j)
                    if (4 * wr + i == 2 * wc + j) tval += acc[i][j][qq];
        }
#pragma unroll
        for (int off = 32; off; off >>= 1) tval += __shfl_down(tval, off);
        if (lane == 0) redbuf[w] = tval;

        // store covM (unnormalized; 1/tr folded into combine scalars below)
#pragma unroll
        for (int i = 0; i < 4; ++i)
#pragma unroll
            for (int j = 0; j < 2; ++j) store_tile(B0, i, j, acc[i][j]);
        if (it < 3) cvt_and_mean(nxt);              // pf->pk frees 26 regs; meanv[nxt]
        barrier_nd();                               // covM + redbuf + meanv[nxt] visible; xc dead

        const float tr = ((redbuf[0] + redbuf[1]) + (redbuf[2] + redbuf[3])) +
                         ((redbuf[4] + redbuf[5]) + (redbuf[6] + redbuf[7]));
        const float inv = 1.0f / tr;
        const float outscale = sqrtf(tr * (1.0f / MCOLS));

        // MM1: RY1 = -0.5*inv^2*(C@C) + 1.5*inv*C        -> B1
        stage(B0, B0, B1, B0, -0.5f * inv * inv, 1.5f * inv, nullptr, 0.f, false, false);
        loadA0(B0);                                 // hoist MM2 af (B0 old; MM1 wrote B1)
        barrier_nd();
        // MM2: RZY1 = 0.25*inv*(C@RY1) - 0.75*RY1        -> B2
        stage(B0, B1, B2, B1, 0.25f * inv, -0.75f, nullptr, 0.f, true, false);
        loadA0(B1);                                 // hoist MM3 af (B1 old; MM2 wrote B2)
        barrier_nd();
        // MM3: RY2 = RY1@RZY1 + 1.5*RY1                  -> B3
        stage(B1, B2, B3, B1, 1.f, 1.5f, nullptr, 0.f, true, false);
        loadA0(B2);                                 // hoist MM4 af (B2 old; MM3 wrote B3)
        barrier_nd();
        // MM4: RZ2 = -0.5*inv*(RZY1@C) - 0.75*inv*C + 1.5*RZY1  -> B1
        stage(B2, B0, B1, B0, -0.5f * inv, -0.75f * inv, B2, 1.5f, true, false);
        loadB0(B3);                                 // hoist MM5 bf (B3 old; MM4 wrote B1)
        barrier_nd();
        // MM5: RT2 = RZ2@RY2 + 2.25*RY2                  -> B0
        stage(B1, B3, B0, B3, 1.f, 2.25f, nullptr, 0.f, false, true);
        loadA0(B3);                                 // hoist MM6 af (B3 old; MM5 wrote B0)
        barrier_nd();                               // T2 ready; B1,B2 (=xc region) dead

        // MM6: O = (1.5*RY2 - 0.5*(RY2@RT2)) * outscale ; upper-tri only
        if (!(wr == 1 && wc < 2)) {
            uint64_t g[4][2];
#pragma unroll
            for (int i = 0; i < 4; ++i)
#pragma unroll
                for (int j = 0; j < 2; ++j) g[i][j] = *own_addr(B3, i, j);
            zacc();
#pragma unroll
            for (int kk = 0; kk < 4; ++kk) {
                const int k0 = kk * 32 + lk * 8;
                v8s af[4], bf[2];
                if (kk == 0) {
#pragma unroll
                    for (int i = 0; i < 4; ++i) af[i] = af0[i];
                } else {
#pragma unroll
                    for (int i = 0; i < 4; ++i)
                        af[i] = *reinterpret_cast<const v8s*>(&B3[(64 * wr + 16 * i + lr) * BPITCH + k0]);
                }
#pragma unroll
                for (int j = 0; j < 2; ++j)
                    bf[j] = *reinterpret_cast<const v8s*>(&B0[(32 * wc + 16 * j + lr) * BPITCH + k0]);
#pragma unroll
                for (int i = 0; i < 4; ++i)
#pragma unroll
                    for (int j = 0; j < 2; ++j)
                        if (4 * wr + i <= 2 * wc + j)
                            acc[i][j] = __builtin_amdgcn_mfma_f32_16x16x32_bf16(af[i], bf[j], acc[i][j], 0, 0, 0);
            }
            float* ob = out + (size_t)bb * KOUT;
#pragma unroll
            for (int i = 0; i < 4; ++i) {
                const int r0 = 64 * wr + 16 * i + 4 * lk;
#pragma unroll
                for (int j = 0; j < 2; ++j) {
                    const int rb = 4 * wr + i, cb = 2 * wc + j;
                    if (rb > cb) continue;
                    const int c = 32 * wc + 16 * j + lr;
                    const v4f o = unq(g[i][j]);
                    float vv[4];
#pragma unroll
                    for (int q = 0; q < 4; ++q)
                        vv[q] = (1.5f * o[q] - 0.5f * acc[i][j][q]) * outscale;
                    if (rb < cb) {
#pragma unroll
                        for (int q = 0; q < 4; ++q) {
                            const int r = r0 + q;
                            ob[r * D - (r * (r + 1)) / 2 + c] = vv[q];
                        }
                    } else {
#pragma unroll
                        for (int q = 0; q < 4; ++q) {
                            const int r = r0 + q;
                            if (r <= c) ob[r * D - (r * (r + 1)) / 2 + c] = vv[q];
                        }
                    }
                }
            }
        }
        if (it < 3) pack_pf();                     // xc(bb+1) into B1/B2, overlaps MM6
    }
}

extern "C" void kernel_launch(void* const* d_in, const int* in_sizes, int n_in,
                              void* d_out, int out_size, void* d_ws, size_t ws_size,
                              hipStream_t stream) {
    const float* x = (const float*)d_in[0];
    float* out = (float*)d_out;
    mpncov_kernel<<<dim3(256), dim3(512), 0, stream>>>(x, out);
}

// Round 14
// 67.895 us; speedup vs baseline: 2.1019x; 1.5396x over previous
//
#include <hip/hip_runtime.h>
#include <hip/hip_bf16.h>
#include <stdint.h>

#define D 128
#define MCOLS 196      // 14*14
#define XPITCH 232     // xc pitch (bf16): 116 dwords == 20 mod 32 -> 2-way (minimum) on b128
#define BPITCH 136     // NS buffer pitch; 68 dwords == 4 mod 32 -> 2-way
#define KOUT 8256      // 128*129/2

typedef short v8s __attribute__((ext_vector_type(8)));
typedef float v4f __attribute__((ext_vector_type(4)));

__device__ __forceinline__ uint32_t cvtpk(float a, float b) {
    __hip_bfloat162 h = __float22bfloat162_rn(make_float2(a, b));   // v_cvt_pk_bf16_f32
    uint32_t u;
    __builtin_memcpy(&u, &h, 4);
    return u;
}
__device__ __forceinline__ uint64_t pk64(float a, float b, float c, float d) {
    return (uint64_t)cvtpk(a, b) | ((uint64_t)cvtpk(c, d) << 32);
}
__device__ __forceinline__ float unlo(uint32_t u) { return __builtin_bit_cast(float, u << 16); }
__device__ __forceinline__ float unhi(uint32_t u) { return __builtin_bit_cast(float, u & 0xFFFF0000u); }

// Barrier WITHOUT vmcnt drain: keeps prefetch global_loads in flight across
// LDS-ordering barriers. lgkmcnt(0) orders all LDS ops; sched_barrier(0)
// prevents post-barrier ds ops hoisting above s_barrier.
__device__ __forceinline__ void barrier_nd() {
    asm volatile("s_waitcnt lgkmcnt(0)" ::: "memory");
    __builtin_amdgcn_s_barrier();
    __builtin_amdgcn_sched_barrier(0);
}

// R8 structure verbatim (the proven no-spill optimum: 512 thr = 8 waves,
// 2/SIMD, 128-VGPR budget, live set ~105) with ONE change: XPITCH 224->232.
// At 224 (112 dwords == 16 mod 32) cov's ds_read_b128 rows alias banks ~8-way;
// 232 (116 == 20 mod 32) is the 2-way free minimum (R12 measured 5.9M vs 8M
// conflicts at this pitch). Costs zero registers.
// Persistent: grid=256 (1 block/CU), 4 batches/block, batch k+1's input
// register-prefetched during batch k's NS chain (no-drain barriers keep the
// loads in flight). Wave grid 2x4: each wave owns 64x32 (4x2 16x16 tiles).
// All NS matrices symmetric -> one row-major LDS copy serves both MFMA
// operands. M = c*I + R split (c exact scalar); linear terms c*R over the
// wave's own region RELOADED from LDS (transposed-contiguous b64).
__global__ __launch_bounds__(512) void mpncov_kernel(const float* __restrict__ x,
                                                     float* __restrict__ out) {
    __shared__ __align__(16) uint16_t lds[4 * D * BPITCH];   // 139264 B
    __shared__ float redbuf[8];

    uint16_t* const B0 = lds;
    uint16_t* const B1 = lds + 1 * D * BPITCH;
    uint16_t* const B2 = lds + 2 * D * BPITCH;
    uint16_t* const B3 = lds + 3 * D * BPITCH;
    // xc (128 x 232 bf16 = 59392 B) overlays B1+B2 (69632 B). Rotation:
    // covM=B0, Y1=B1, ZY1=B2, Y2=B3, Z2=B1, T2=B0 -> B2 dead after MM4,
    // B1 dead after MM5 -> pack(k+1) runs during/after MM6.
    uint16_t (*const xc)[XPITCH] = reinterpret_cast<uint16_t(*)[XPITCH]>(B1);

    const int tid = threadIdx.x;
    const int lane = tid & 63;
    const int w = tid >> 6, wr = w >> 2, wc = w & 3;   // 2x4 wave grid
    const int lr = lane & 15, lk = lane >> 4;
    const int pr = tid >> 2, pq = tid & 3;             // prefetch: 4 threads/row

    // ---- cross-batch prefetch state: 49 float4 per row, 12(+1 tail) per thread ----
    float4 pf[12]; float4 pfT;

    auto issue_pf = [&](int bbn) {
        const float4* p4 = reinterpret_cast<const float4*>(x + (size_t)bbn * (D * MCOLS)) + 49 * pr;
#pragma unroll
        for (int i = 0; i < 12; ++i) pf[i] = p4[pq + 4 * i];
        if (pq == 0) pfT = p4[48];
    };
    // mean via 4-lane shfl, center exactly in f32, pack bf16, write xc + zero K-pad
    auto pack_pf = [&]() {
        float s = 0.f;
#pragma unroll
        for (int i = 0; i < 12; ++i) s += (pf[i].x + pf[i].y) + (pf[i].z + pf[i].w);
        if (pq == 0) s += (pfT.x + pfT.y) + (pfT.z + pfT.w);
        s += __shfl_xor(s, 1); s += __shfl_xor(s, 2);
        const float m = s * (1.0f / MCOLS);
#pragma unroll
        for (int i = 0; i < 12; ++i)
            *reinterpret_cast<uint64_t*>(&xc[pr][4 * (pq + 4 * i)]) =
                pk64(pf[i].x - m, pf[i].y - m, pf[i].z - m, pf[i].w - m);
        if (pq == 0)
            *reinterpret_cast<uint64_t*>(&xc[pr][192]) =
                pk64(pfT.x - m, pfT.y - m, pfT.z - m, pfT.w - m);
        // zero K-pad cols 196..231 (9 b64 slots/row, 4 threads: pq, pq+4, pq==0 -> 8)
        *reinterpret_cast<uint64_t*>(&xc[pr][MCOLS + 4 * pq]) = 0ull;
        *reinterpret_cast<uint64_t*>(&xc[pr][MCOLS + 4 * (pq + 4)]) = 0ull;
        if (pq == 0) *reinterpret_cast<uint64_t*>(&xc[pr][MCOLS + 32]) = 0ull;
    };

    v4f acc[4][2];
    auto zacc = [&]() {
#pragma unroll
        for (int i = 0; i < 4; ++i)
#pragma unroll
            for (int j = 0; j < 2; ++j) acc[i][j] = v4f{0.f, 0.f, 0.f, 0.f};
    };
    auto matmul = [&](const uint16_t* P, const uint16_t* Q) {
        zacc();
#pragma unroll
        for (int kk = 0; kk < 4; ++kk) {
            const int k0 = kk * 32 + lk * 8;
            v8s af[4], bf[2];
#pragma unroll
            for (int i = 0; i < 4; ++i)
                af[i] = *reinterpret_cast<const v8s*>(&P[(64 * wr + 16 * i + lr) * BPITCH + k0]);
#pragma unroll
            for (int j = 0; j < 2; ++j)
                bf[j] = *reinterpret_cast<const v8s*>(&Q[(32 * wc + 16 * j + lr) * BPITCH + k0]);
#pragma unroll
            for (int i = 0; i < 4; ++i)
#pragma unroll
                for (int j = 0; j < 2; ++j)
                    acc[i][j] = __builtin_amdgcn_mfma_f32_16x16x32_bf16(af[i], bf[j], acc[i][j], 0, 0, 0);
        }
    };
    // own-region reload: value quad M[r0..r0+3][c] == one b64 at transposed slot
    auto load_own = [&](const uint16_t* src, int i, int j) -> v4f {
        const int r0 = 64 * wr + 16 * i + 4 * lk;
        const int c  = 32 * wc + 16 * j + lr;
        const uint64_t g = *reinterpret_cast<const uint64_t*>(&src[c * BPITCH + r0]);
        return v4f{unlo((uint32_t)g), unhi((uint32_t)g),
                   unlo((uint32_t)(g >> 32)), unhi((uint32_t)(g >> 32))};
    };
    auto store_tile = [&](uint16_t* dst, int i, int j, const v4f& v) {   // transposed b64
        const int r0 = 64 * wr + 16 * i + 4 * lk;
        const int c  = 32 * wc + 16 * j + lr;
        *reinterpret_cast<uint64_t*>(&dst[c * BPITCH + r0]) = pk64(v[0], v[1], v[2], v[3]);
    };

    // ---- prologue: stage batch (4*blockIdx.x) ----
    issue_pf(4 * blockIdx.x);
    pack_pf();

    for (int it = 0; it < 4; ++it) {
        const int bb = 4 * blockIdx.x + it;
        barrier_nd();                               // xc(bb) ready

        if (it < 3) {                               // issue next batch's loads NOW;
            issue_pf(bb + 1);                       // they stay in flight across all
            __builtin_amdgcn_sched_barrier(0);      // no-drain barriers below
        }

        // ---- cov: covM = xc @ xc^T (centered, K padded to 224) ----
        zacc();
#pragma unroll
        for (int kk = 0; kk < 7; ++kk) {
            const int k0 = kk * 32 + lk * 8;
            v8s af[4], bf[2];
#pragma unroll
            for (int i = 0; i < 4; ++i)
                af[i] = *reinterpret_cast<const v8s*>(&xc[64 * wr + 16 * i + lr][k0]);
#pragma unroll
            for (int j = 0; j < 2; ++j)
                bf[j] = *reinterpret_cast<const v8s*>(&xc[32 * wc + 16 * j + lr][k0]);
#pragma unroll
            for (int i = 0; i < 4; ++i)
#pragma unroll
                for (int j = 0; j < 2; ++j)
                    acc[i][j] = __builtin_amdgcn_mfma_f32_16x16x32_bf16(af[i], bf[j], acc[i][j], 0, 0, 0);
        }

        // trace (C/D layout: col=lane&15, row=(lane>>4)*4+q)
        float tval = 0.f;
        if ((lr >> 2) == lk) {
            const int qq = lr & 3;
#pragma unroll
            for (int i = 0; i < 4; ++i)
#pragma unroll
                for (int j = 0; j < 2; ++j)
                    if (4 * wr + i == 2 * wc + j) tval += acc[i][j][qq];
        }
#pragma unroll
        for (int off = 32; off; off >>= 1) tval += __shfl_down(tval, off);
        if (lane == 0) redbuf[w] = tval;

        // store covM (unnormalized; 1/tr folded into combine scalars below)
#pragma unroll
        for (int i = 0; i < 4; ++i)
#pragma unroll
            for (int j = 0; j < 2; ++j) store_tile(B0, i, j, acc[i][j]);
        barrier_nd();                               // covM + redbuf visible; xc dead

        const float tr = ((redbuf[0] + redbuf[1]) + (redbuf[2] + redbuf[3])) +
                         ((redbuf[4] + redbuf[5]) + (redbuf[6] + redbuf[7]));
        const float inv = 1.0f / tr;
        const float outscale = sqrtf(tr * (1.0f / MCOLS));
        const float s11 = -0.5f * inv * inv, s12 = 1.5f * inv;
        const float s21 = 0.25f * inv;
        const float s41 = -0.5f * inv, s42 = -0.75f * inv;

        // MM1: RY1 = -0.5*inv^2*(C@C) + 1.5*inv*C        -> B1
        matmul(B0, B0);
#pragma unroll
        for (int i = 0; i < 4; ++i)
#pragma unroll
            for (int j = 0; j < 2; ++j) {
                const v4f o = load_own(B0, i, j);
                store_tile(B1, i, j, v4f{s11 * acc[i][j][0] + s12 * o[0],
                                         s11 * acc[i][j][1] + s12 * o[1],
                                         s11 * acc[i][j][2] + s12 * o[2],
                                         s11 * acc[i][j][3] + s12 * o[3]});
            }
        barrier_nd();

        // MM2: RZY1 = 0.25*inv*(C@RY1) - 0.75*RY1        -> B2
        matmul(B0, B1);
#pragma unroll
        for (int i = 0; i < 4; ++i)
#pragma unroll
            for (int j = 0; j < 2; ++j) {
                const v4f o = load_own(B1, i, j);
                store_tile(B2, i, j, v4f{s21 * acc[i][j][0] - 0.75f * o[0],
                                         s21 * acc[i][j][1] - 0.75f * o[1],
                                         s21 * acc[i][j][2] - 0.75f * o[2],
                                         s21 * acc[i][j][3] - 0.75f * o[3]});
            }
        barrier_nd();

        // MM3: RY2 = RY1@RZY1 + 1.5*RY1                  -> B3
        matmul(B1, B2);
#pragma unroll
        for (int i = 0; i < 4; ++i)
#pragma unroll
            for (int j = 0; j < 2; ++j) {
                const v4f o = load_own(B1, i, j);
                store_tile(B3, i, j, v4f{acc[i][j][0] + 1.5f * o[0],
                                         acc[i][j][1] + 1.5f * o[1],
                                         acc[i][j][2] + 1.5f * o[2],
                                         acc[i][j][3] + 1.5f * o[3]});
            }
        barrier_nd();

        // MM4: RZ2 = -0.5*inv*(RZY1@C) - 0.75*inv*C + 1.5*RZY1   -> B1
        matmul(B2, B0);
#pragma unroll
        for (int i = 0; i < 4; ++i)
#pragma unroll
            for (int j = 0; j < 2; ++j) {
                const v4f oc = load_own(B0, i, j);
                const v4f oz = load_own(B2, i, j);
                store_tile(B1, i, j, v4f{s41 * acc[i][j][0] + s42 * oc[0] + 1.5f * oz[0],
                                         s41 * acc[i][j][1] + s42 * oc[1] + 1.5f * oz[1],
                                         s41 * acc[i][j][2] + s42 * oc[2] + 1.5f * oz[2],
                                         s41 * acc[i][j][3] + s42 * oc[3] + 1.5f * oz[3]});
            }
        barrier_nd();

        // MM5: RT2 = RZ2@RY2 + 2.25*RY2                  -> B0
        matmul(B1, B3);
#pragma unroll
        for (int i = 0; i < 4; ++i)
#pragma unroll
            for (int j = 0; j < 2; ++j) {
                const v4f o = load_own(B3, i, j);
                store_tile(B0, i, j, v4f{acc[i][j][0] + 2.25f * o[0],
                                         acc[i][j][1] + 2.25f * o[1],
                                         acc[i][j][2] + 2.25f * o[2],
                                         acc[i][j][3] + 2.25f * o[3]});
            }
        barrier_nd();                              // T2 ready; B1,B2 (=xc region) dead

        // MM6: O = (1.5*RY2 - 0.5*(RY2@RT2)) * outscale ; upper-tri only
        if (!(wr == 1 && wc < 2)) {
            zacc();
#pragma unroll
            for (int kk = 0; kk < 4; ++kk) {
                const int k0 = kk * 32 + lk * 8;
                v8s af[4], bf[2];
#pragma unroll
                for (int i = 0; i < 4; ++i)
                    af[i] = *reinterpret_cast<const v8s*>(&B3[(64 * wr + 16 * i + lr) * BPITCH + k0]);
#pragma unroll
                for (int j = 0; j < 2; ++j)
                    bf[j] = *reinterpret_cast<const v8s*>(&B0[(32 * wc + 16 * j + lr) * BPITCH + k0]);
#pragma unroll
                for (int i = 0; i < 4; ++i)
#pragma unroll
                    for (int j = 0; j < 2; ++j)
                        if (4 * wr + i <= 2 * wc + j)
                            acc[i][j] = __builtin_amdgcn_mfma_f32_16x16x32_bf16(af[i], bf[j], acc[i][j], 0, 0, 0);
            }
            float* ob = out + (size_t)bb * KOUT;
#pragma unroll
            for (int i = 0; i < 4; ++i) {
                const int r0 = 64 * wr + 16 * i + 4 * lk;
#pragma unroll
                for (int j = 0; j < 2; ++j) {
                    const int rb = 4 * wr + i, cb = 2 * wc + j;
                    if (rb > cb) continue;
                    const int c = 32 * wc + 16 * j + lr;
                    const v4f o = load_own(B3, i, j);
                    float vv[4];
#pragma unroll
                    for (int q = 0; q < 4; ++q)
                        vv[q] = (1.5f * o[q] - 0.5f * acc[i][j][q]) * outscale;
                    if (rb < cb) {
#pragma unroll
                        for (int q = 0; q < 4; ++q) {
                            const int r = r0 + q;
                            ob[r * D - (r * (r + 1)) / 2 + c] = vv[q];
                        }
                    } else {
#pragma unroll
                        for (int q = 0; q < 4; ++q) {
                            const int r = r0 + q;
                            if (r <= c) ob[r * D - (r * (r + 1)) / 2 + c] = vv[q];
                        }
                    }
                }
            }
        }
        if (it < 3) pack_pf();                     // xc(bb+1) into B1/B2, overlaps MM6
    }
}

extern "C" void kernel_launch(void* const* d_in, const int* in_sizes, int n_in,
                              void* d_out, int out_size, void* d_ws, size_t ws_size,
                              hipStream_t stream) {
    const float* x = (const float*)d_in[0];
    float* out = (float*)d_out;
    mpncov_kernel<<<dim3(256), dim3(512), 0, stream>>>(x, out);
}